// Round 7
// baseline (303.736 us; speedup 1.0000x reference)
//
#include <hip/hip_runtime.h>
#include <math.h>

// MS-SSIM loss, fp32, (32,3,384,384), 5 scales, win=11 sigma=1.5, VALID.
// R15: depth-7 rolling prefetch + bound 5, and B+final fusion.
// R14 accounting: A(pyr+s0)=101, B(s1-4)~27, final~3 -> ~85us of
// fixed launch/harness overhead explains the "hidden rest" of ALL
// rounds. A is issue-starved (busy 58us over 101us, occ 42% = bound-4
// cap). R12 only tested bound DOWN; R10's rolling D=4 failed on
// prefetch distance (250cy < latency). D=7: distance ~770cy covers
// L2/L3, footprint = stage 28 + acc 32 + QQ 12 + temps ~14 = 86 regs
// -> fits launch_bounds(256,5) (budget 102) -> 5 waves/SIMD.
// B: final fused via last-block done-counter (threadfence + volatile).

namespace {

constexpr int NIMG = 96;            // B*C = 32*3
constexpr float TWO_C1 = 13.005f;   // 2*(0.01*255)^2
constexpr float TWO_C2 = 117.045f;  // 2*(0.03*255)^2
constexpr int TOTAL_B = 34 * NIMG;  // blocks in ssim_rest

// gauss(11, sigma=1.5), normalized (matches expf path to fp32 ulp).
__device__ constexpr float GW[11] = {
    0.00102838f, 0.00759875f, 0.03600077f, 0.10936070f, 0.21300553f,
    0.26601172f,
    0.21300553f, 0.10936070f, 0.03600077f, 0.00759875f, 0.00102838f};

typedef float f2 __attribute__((ext_vector_type(2)));
typedef float f4 __attribute__((ext_vector_type(4)));

// ---- VOP3P packed fp32 with op_sel variants ----
// op_sel[i]: half feeding LOW result (0=lo); op_sel_hi[i]: half feeding HIGH.
__device__ __forceinline__ f2 pk_mul(f2 a, f2 b) {
  f2 d;
  asm("v_pk_mul_f32 %0, %1, %2" : "=v"(d) : "v"(a), "v"(b));
  return d;
}
// d = a * splat_lo(b)  (init of hblur chain, j=0 even term)
__device__ __forceinline__ f2 pk_mul_s1lo(f2 a, f2 b) {
  f2 d;
  asm("v_pk_mul_f32 %0, %1, %2 op_sel:[0,0] op_sel_hi:[1,0]"
      : "=v"(d) : "v"(a), "v"(b));
  return d;
}
// d += splat_lo(q) * p   (vblur tap: weight splat from pair reg)
__device__ __forceinline__ void fma_w(f2& d, f2 q, f2 p) {
  asm("v_pk_fma_f32 %0, %1, %2, %0 op_sel:[0,0,0] op_sel_hi:[0,1,1]"
      : "+v"(d) : "v"(q), "v"(p));
}
// d += q * splat_lo(t)
__device__ __forceinline__ void fma_nl(f2& d, f2 q, f2 t) {
  asm("v_pk_fma_f32 %0, %1, %2, %0 op_sel:[0,0,0] op_sel_hi:[1,0,1]"
      : "+v"(d) : "v"(q), "v"(t));
}
// d += q * splat_hi(t)
__device__ __forceinline__ void fma_nh(f2& d, f2 q, f2 t) {
  asm("v_pk_fma_f32 %0, %1, %2, %0 op_sel:[0,1,0] op_sel_hi:[1,1,1]"
      : "+v"(d) : "v"(q), "v"(t));
}
// d += swap(q) * splat_lo(t)
__device__ __forceinline__ void fma_sl(f2& d, f2 q, f2 t) {
  asm("v_pk_fma_f32 %0, %1, %2, %0 op_sel:[1,0,0] op_sel_hi:[0,0,1]"
      : "+v"(d) : "v"(q), "v"(t));
}
// d += swap(q) * splat_hi(t)
__device__ __forceinline__ void fma_sh(f2& d, f2 q, f2 t) {
  asm("v_pk_fma_f32 %0, %1, %2, %0 op_sel:[1,1,0] op_sel_hi:[0,1,1]"
      : "+v"(d) : "v"(q), "v"(t));
}

// lane i <- lane i+1 (wave_shl:1); lane 63 gets 0. HW-verified (R5-R7).
__device__ __forceinline__ float wshl1(float v) {
  return __int_as_float(__builtin_amdgcn_mov_dpp(
      __float_as_int(v), 0x130, 0xF, 0xF, true));
}
__device__ __forceinline__ f2 wshl1v(f2 v) {
  f2 r;
  r.x = wshl1(v.x);
  r.y = wshl1(v.y);
  return r;
}

struct SPtrs {
  const float* ip[4];  // levels 1..4, u/w interleaved (u0,u1,w0,w1)/colpair
};

// Depth-7 rolling register prefetch: row j+7's load issues at iteration j
// (consumed-then-overwritten slot j%7, static after unroll). Prefetch
// distance = 7 iterations (~770cy) > L2/L3 latency; in-flight regs = 7
// rows (28 VGPR for s0, 28 for s>=1). BASE: two f2 loads/row (X0,Y0),
// u/w formed in-kernel. !BASE: one f4 load/row (Pu=v.xy, Pw=v.zw).
template <bool BASE, bool CLAMP>
__device__ __forceinline__ void vblur(const float* __restrict__ XP,
                                      const float* __restrict__ YP, int row0,
                                      int W2, int H, int cp, f2 (&AU)[4],
                                      f2 (&AW)[4], f2 (&BU)[4], f2 (&BW)[4],
                                      const f2 (&QQ)[6]) {
  const f2* PA = (const f2*)XP;
  const f2* PB = (const f2*)YP;
  const f4* PV = (const f4*)XP;
  f2 sa[7], sb[7];
  f4 sv[7];
#pragma unroll
  for (int j = 0; j < 7; ++j) {
    int rin = row0 + j;
    if (CLAMP) rin = rin < H - 1 ? rin : H - 1;
    const int off = rin * W2 + cp;      // 32-bit affine (fits: <= 384*192)
    if (BASE) {
      sa[j] = PA[off];
      sb[j] = PB[off];
    } else {
      sv[j] = PV[off];
    }
  }
  __builtin_amdgcn_sched_barrier(0);    // pin prologue loads above loop
#pragma unroll
  for (int j = 0; j < 14; ++j) {
    f2 Pu, Pw;
    if (BASE) {
      f2 pa = sa[j % 7], pb = sb[j % 7];
      Pu = pa + pb;
      Pw = pa - pb;
    } else {
      f4 v = sv[j % 7];
      Pu.x = v.x; Pu.y = v.y;
      Pw.x = v.z; Pw.y = v.w;
    }
    if (j + 7 < 14) {   // prefetch 7 rows ahead into the freed slot
      int rin = row0 + j + 7;
      if (CLAMP) rin = rin < H - 1 ? rin : H - 1;
      const int off = rin * W2 + cp;
      if (BASE) {
        sa[j % 7] = PA[off];
        sb[j % 7] = PB[off];
      } else {
        sv[j % 7] = PV[off];
      }
    }
    f2 Qu = pk_mul(Pu, Pu), Qw = pk_mul(Pw, Pw);
#pragma unroll
    for (int i = 0; i < 4; ++i) {
      const int k = j - i;
      if (k >= 0 && k <= 10) {
        const int qi = k <= 5 ? k : 10 - k;     // G[k] = QQ[qi].x
        fma_w(AU[i], QQ[qi], Pu);
        fma_w(AW[i], QQ[qi], Pw);
        fma_w(BU[i], QQ[qi], Qu);
        fma_w(BW[i], QQ[qi], Qw);
      }
    }
  }
}

// One SSIM tile: 64 lanes x 2 cols = 128 input cols -> up to 118 outputs;
// 4 output rows/wave, 4 waves = 16 output rows (26 input rows) per block.
template <bool BASE>
__device__ __forceinline__ void ssim_tile(const float* __restrict__ XP,
                                          const float* __restrict__ YP,
                                          int H, int x0, int tw, int by,
                                          int s, int img,
                                          float* __restrict__ acc) {
  __shared__ float red[2][4];
  const int W2 = H >> 1, OH = H - 10;
  const int t = threadIdx.x;
  const int lane = t & 63, wv = t >> 6;
  int cp = (x0 >> 1) + lane;
  cp = cp < W2 - 1 ? cp : W2 - 1;
  const int row0 = by * 16 + wv * 4;

  // Weight pairs QQ[n] = (G[n], G[n-1]), G[-1]=0. All other weight forms
  // derived via op_sel (splat-lo / swap) using G[k] = G[10-k].
  f2 QQ[6];
  QQ[0].x = GW[0]; QQ[0].y = 0.f;
#pragma unroll
  for (int n = 1; n < 6; ++n) { QQ[n].x = GW[n]; QQ[n].y = GW[n - 1]; }

  float ssim_s = 0.f, cs_s = 0.f;

  if (row0 < OH) {
    f2 AU[4] = {}, AW[4] = {}, BU[4] = {}, BW[4] = {};
    const bool noclamp = (row0 + 13 <= H - 1);
    if (noclamp) vblur<BASE, false>(XP, YP, row0, W2, H, cp, AU, AW, BU, BW, QQ);
    else         vblur<BASE, true >(XP, YP, row0, W2, H, cp, AU, AW, BU, BW, QQ);

    // hblur: 2 outputs/lane, 5 two-col shift steps.
    // O.x = sum_k G[k]*V[2c+k], O.y = sum_k G[k]*V[2c+1+k]; contribution of
    // t_j=(e,o)=(V[2c+2j],V[2c+2j+1]): (G[2j],G[2j-1])*e + (G[2j+1],G[2j])*o.
    auto hb = [&QQ](f2 tt) -> f2 {
      f2 h = pk_mul_s1lo(QQ[0], tt);   // j=0: (G0,0)*e
      fma_nh(h, QQ[1], tt);            // j=0: (G1,G0)*o
      tt = wshl1v(tt);
      fma_nl(h, QQ[2], tt);            // j=1: (G2,G1)*e
      fma_nh(h, QQ[3], tt);            // j=1: (G3,G2)*o
      tt = wshl1v(tt);
      fma_nl(h, QQ[4], tt);            // j=2: (G4,G3)*e
      fma_nh(h, QQ[5], tt);            // j=2: (G5,G4)*o
      tt = wshl1v(tt);
      fma_sl(h, QQ[5], tt);            // j=3: (G6,G5)=(G4,G5)=swap(QQ5)
      fma_sh(h, QQ[4], tt);            // j=3: (G7,G6)=(G3,G4)=swap(QQ4)
      tt = wshl1v(tt);
      fma_sl(h, QQ[3], tt);            // j=4: (G8,G7)=swap(QQ3)
      fma_sh(h, QQ[2], tt);            // j=4: (G9,G8)=swap(QQ2)
      tt = wshl1v(tt);
      fma_sl(h, QQ[1], tt);            // j=5: (G10,G9)=swap(QQ1)
      fma_sh(h, QQ[0], tt);            // j=5: (0,G10)=swap(QQ0)
      return h;
    };

    const bool vx = (2 * lane) < tw;
    const bool vy = (2 * lane + 1) < tw;
#pragma unroll
    for (int i = 0; i < 4; ++i) {
      if (row0 + i < OH) {
        f2 bU = hb(AU[i]), bW = hb(AW[i]);
        f2 bU2 = hb(BU[i]), bW2 = hb(BW[i]);
        f2 m2u = pk_mul(bU, bU), m2w = pk_mul(bW, bW);
        f2 Pm = m2u - m2w;           // 4*mu1*mu2
        f2 Qm = m2u + m2w;           // 2*(mu1^2+mu2^2)
        f2 Am = bU2 - bW2;           // 4*E[xy]
        f2 Bm = bU2 + bW2;           // 2*(E[xx]+E[yy])
        float csx = (Am.x - Pm.x + TWO_C2) *
                    __builtin_amdgcn_rcpf(Bm.x - Qm.x + TWO_C2);
        float lx = (Pm.x + TWO_C1) * __builtin_amdgcn_rcpf(Qm.x + TWO_C1);
        float csy = (Am.y - Pm.y + TWO_C2) *
                    __builtin_amdgcn_rcpf(Bm.y - Qm.y + TWO_C2);
        float ly = (Pm.y + TWO_C1) * __builtin_amdgcn_rcpf(Qm.y + TWO_C1);
        if (vx) { cs_s += csx; ssim_s += lx * csx; }
        if (vy) { cs_s += csy; ssim_s += ly * csy; }
      }
    }
  }

  // ---- reduce: wave shuffle -> LDS -> 2 atomics/block ----
#pragma unroll
  for (int off = 32; off > 0; off >>= 1) {
    ssim_s += __shfl_down(ssim_s, off);
    cs_s += __shfl_down(cs_s, off);
  }
  if (lane == 0) { red[0][wv] = ssim_s; red[1][wv] = cs_s; }
  __syncthreads();
  if (t == 0) {
    atomicAdd(&acc[(2 * s + 0) * NIMG + img],
              red[0][0] + red[0][1] + red[0][2] + red[0][3]);
    atomicAdd(&acc[(2 * s + 1) * NIMG + img],
              red[1][0] + red[1][1] + red[1][2] + red[1][3]);
  }
}

// Coalesced pyramid body: one wave owns a 64x16 source tile (two 8-row
// batches); dwordx4 loads, float4 stores, u/w interleaved per col-pair.
__device__ __forceinline__ void pyramid_body(
    const float* __restrict__ X, const float* __restrict__ Y,
    float* __restrict__ i1, float* __restrict__ i2,
    float* __restrict__ i3, float* __restrict__ i4, int img, int bx) {
  const int t = threadIdx.x;
  const int wv = t >> 6, lane = t & 63;
  const int tidx = bx * 4 + wv;             // 0..143
  const int tx = tidx % 6, ty = tidx / 6;   // 6 x 24 tiles of 64x16
  const int r = lane >> 4, c = lane & 15;

  const float* Xs = X + (size_t)img * 384 * 384;
  const float* Ys = Y + (size_t)img * 384 * 384;
  f4* p1 = (f4*)i1 + (size_t)img * 192 * 96;
  f4* p2 = (f4*)i2 + (size_t)img * 96 * 48;
  f4* p3 = (f4*)i3 + (size_t)img * 48 * 24;
  f4* p4 = (f4*)i4 + (size_t)img * 24 * 12;

  float h4u = 0.f, h4w = 0.f;
#pragma unroll
  for (int b = 0; b < 2; ++b) {
    const int gr = ty * 16 + b * 8 + 2 * r;
    const int gc = tx * 64 + 4 * c;
    f4 xu = *(const f4*)&Xs[(size_t)gr * 384 + gc];
    f4 xv = *(const f4*)&Xs[(size_t)(gr + 1) * 384 + gc];
    f4 yu = *(const f4*)&Ys[(size_t)gr * 384 + gc];
    f4 yv = *(const f4*)&Ys[(size_t)(gr + 1) * 384 + gc];
    float ax = 0.25f * (xu.x + xu.y + xv.x + xv.y);   // L1 of X @ C1
    float bx2 = 0.25f * (xu.z + xu.w + xv.z + xv.w);  // L1 of X @ C1+1
    float ay = 0.25f * (yu.x + yu.y + yv.x + yv.y);
    float by2 = 0.25f * (yu.z + yu.w + yv.z + yv.w);
    float u0 = ax + ay, u1v = bx2 + by2, w0 = ax - ay, w1v = bx2 - by2;
    {  // L1: row ty*8+4b+r, colpair tx*16+c  (16 lanes x 16B = 256B)
      f4 st; st.x = u0; st.y = u1v; st.z = w0; st.w = w1v;
      p1[(size_t)(ty * 8 + b * 4 + r) * 96 + tx * 16 + c] = st;
    }
    // L2: horizontal in-lane, vertical via r-pair (lane^16).
    float hu = u0 + u1v, hw = w0 + w1v;
    float su = 0.25f * (hu + __shfl_xor(hu, 16));     // L2 @ (R2, tx*16+c)
    float sw = 0.25f * (hw + __shfl_xor(hw, 16));
    float suh = __shfl_xor(su, 1), swh = __shfl_xor(sw, 1);
    if ((r & 1) == 0 && (c & 1) == 0) {
      f4 st; st.x = su; st.y = suh; st.z = sw; st.w = swh;
      p2[(size_t)(ty * 4 + 2 * b + (r >> 1)) * 48 + tx * 8 + (c >> 1)] = st;
    }
    // L3: col pair via lane^1, row pair via lane^32 (r 0<->2).
    float au = su + __shfl_xor(su, 1);
    float aw = sw + __shfl_xor(sw, 1);
    float u3 = 0.25f * (au + __shfl_xor(au, 32));     // L3 @ (ty*2+b, tx*8+(c>>1))
    float w3 = 0.25f * (aw + __shfl_xor(aw, 32));
    float u3h = __shfl_xor(u3, 2), w3h = __shfl_xor(w3, 2);
    if (r == 0 && (c & 3) == 0) {
      f4 st; st.x = u3; st.y = u3h; st.z = w3; st.w = w3h;
      p3[(size_t)(ty * 2 + b) * 24 + tx * 4 + (c >> 2)] = st;
    }
    // L4: col pair via lane^2, row pair across batches (kept in regs).
    float hu4 = u3 + __shfl_xor(u3, 2);
    float hw4 = w3 + __shfl_xor(w3, 2);
    if (b == 0) {
      h4u = hu4; h4w = hw4;
    } else {
      float l4u = 0.25f * (h4u + hu4), l4w = 0.25f * (h4w + hw4);
      float l4uh = __shfl_xor(l4u, 4), l4wh = __shfl_xor(l4w, 4);
      if (r == 0 && (c & 7) == 0) {
        f4 st; st.x = l4u; st.y = l4uh; st.z = l4w; st.w = l4wh;
        p4[(size_t)ty * 12 + tx * 2 + (c >> 3)] = st;
      }
    }
  }
}

// Kernel A: blocks x<36 run the pyramid, x>=36 run s0-SSIM tiles.
__global__ __launch_bounds__(256, 5) void fused_pyr_s0(
    const float* __restrict__ X, const float* __restrict__ Y,
    float* __restrict__ i1, float* __restrict__ i2,
    float* __restrict__ i3, float* __restrict__ i4,
    float* __restrict__ acc) {
  const int img = blockIdx.y;
  if (blockIdx.x < 36) {
    pyramid_body(X, Y, i1, i2, i3, i4, img, blockIdx.x);
    return;
  }
  const int lt = blockIdx.x - 36;        // 0..95: s0 tiles, 4 x 24
  const int tx = lt & 3, by = lt >> 2;
  const int x0 = tx * 94;
  int tw = 374 - x0;
  tw = tw < 94 ? tw : 94;
  ssim_tile<true>(X + (size_t)img * 384 * 384, Y + (size_t)img * 384 * 384,
                  384, x0, tw, by, 0, img, acc);
}

// Kernel B: scales 1..4 (need pyramid outputs) + fused final via
// last-block done-counter. Tiles/img: s1 24, s2 6, s3 3, s4 1 (34).
__global__ __launch_bounds__(256, 5) void ssim_rest(SPtrs sp,
                                                    float* __restrict__ acc,
                                                    int* __restrict__ ctr,
                                                    float* __restrict__ out) {
  const int img = blockIdx.y;
  const int tile = 96 + blockIdx.x;      // 96..129
  int s;
  if (tile < 120) s = 1;
  else if (tile < 126) s = 2;
  else if (tile < 129) s = 3;
  else s = 4;
  const int tstart[5] = {0, 96, 120, 126, 129};
  const int HH[5] = {384, 192, 96, 48, 24};
  const int NTX[5] = {4, 2, 1, 1, 1};
  const int TWM[5] = {94, 92, 86, 38, 14};
  const int lt = tile - tstart[s];
  const int H = HH[s], OW = H - 10;
  const int tx = lt % NTX[s], by = lt / NTX[s];
  const int x0 = tx * TWM[s];
  const int tw = (TWM[s] < OW - x0) ? TWM[s] : OW - x0;
  const float* XP = sp.ip[s - 1] + (size_t)img * H * (H >> 1) * 4;
  ssim_tile<false>(XP, nullptr, H, x0, tw, by, s, img, acc);

  // ---- last-block final reduction ----
  const int t = threadIdx.x;
  __shared__ int sh_last;
  if (t == 0) {
    __threadfence();                      // release our acc atomics
    int old = atomicAdd(ctr, 1);
    sh_last = (old == TOTAL_B - 1) ? 1 : 0;
  }
  __syncthreads();
  if (sh_last) {
    __threadfence();                      // acquire all blocks' atomics
    __shared__ float prods[NIMG];
    const float wts[5] = {0.0448f, 0.2856f, 0.3001f, 0.2363f, 0.1333f};
    const float inv_npix[5] = {1.f / (374.f * 374.f), 1.f / (182.f * 182.f),
                               1.f / (86.f * 86.f),  1.f / (38.f * 38.f),
                               1.f / (14.f * 14.f)};
    if (t < NIMG) {
      const volatile float* vacc = acc;   // bypass L1 (sc0 loads)
      float p = 1.f;
#pragma unroll
      for (int q = 0; q < 5; ++q) {
        float sum = (q < 4) ? vacc[(q * 2 + 1) * NIMG + t]
                            : vacc[(q * 2 + 0) * NIMG + t];
        float m = sum * inv_npix[q];
        m = m > 0.f ? m : 0.f;
        p *= powf(m, wts[q]);
      }
      prods[t] = p;
    }
    __syncthreads();
    if (t == 0) {
      float sm = 0.f;
      for (int i = 0; i < NIMG; ++i) sm += prods[i];
      out[0] = 1.f - sm / (float)NIMG;
    }
  }
}

}  // namespace

extern "C" void kernel_launch(void* const* d_in, const int* in_sizes, int n_in,
                              void* d_out, int out_size, void* d_ws,
                              size_t ws_size, hipStream_t stream) {
  const float* X0 = (const float*)d_in[0];
  const float* Y0 = (const float*)d_in[1];
  float* out = (float*)d_out;
  float* ws = (float*)d_ws;

  // Interleaved u/w planes: level L holds 2*H*W floats.
  const size_t L1 = (size_t)NIMG * 192 * 192 * 2;
  const size_t L2 = (size_t)NIMG * 96 * 96 * 2;
  const size_t L3 = (size_t)NIMG * 48 * 48 * 2;
  const size_t L4 = (size_t)NIMG * 24 * 24 * 2;

  float* i1 = ws;
  float* i2 = i1 + L1;
  float* i3 = i2 + L2;
  float* i4 = i3 + L3;
  float* acc = i4 + L4;           // 10*NIMG floats
  int* ctr = (int*)(acc + 10 * NIMG);  // done-counter (1 int)

  hipMemsetAsync(acc, 0, (10 * NIMG + 1) * sizeof(float), stream);

  fused_pyr_s0<<<dim3(36 + 96, NIMG), dim3(256), 0, stream>>>(
      X0, Y0, i1, i2, i3, i4, acc);

  SPtrs sp;
  sp.ip[0] = i1; sp.ip[1] = i2; sp.ip[2] = i3; sp.ip[3] = i4;

  ssim_rest<<<dim3(34, NIMG), dim3(256), 0, stream>>>(sp, acc, ctr, out);
}

// Round 9
// 215.387 us; speedup vs baseline: 1.4102x; 1.4102x over previous
//
#include <hip/hip_runtime.h>
#include <math.h>

// MS-SSIM loss, fp32, (32,3,384,384), 5 scales, win=11 sigma=1.5, VALID.
// R17: mixing via stream order, not device sync. R16 (spin-wait on a
// pyramid flag) hung: G16 -- dispatch order is UNDEFINED; waiters can
// occupy every CU slot before their producer dispatches. Reverted.
// Validated facts: s1-4 tiles standalone = 110us @ 3.5% per-wave issue
// (homogeneous latency-bound blocks); same tiles ~25us marginal when
// mixed with s0 blocks (R12). The stream already gives the dependency:
// kernel B runs after ALL of A. So move 34 of 96 s0 tiles (which don't
// need the pyramid) from A into B:
//   A = pyramid(36) + s0 tiles 0..61   -> still mixed, smaller
//   B = rest s1-4 (34, dispatched first) + s0 tiles 62..95 -> rest's
//       stalls hide under s0 VALU work. No sync primitives anywhere.
// Everything else identical to R14 (best passing: 221us).

namespace {

constexpr int NIMG = 96;            // B*C = 32*3
constexpr float TWO_C1 = 13.005f;   // 2*(0.01*255)^2
constexpr float TWO_C2 = 117.045f;  // 2*(0.03*255)^2
constexpr int PYR_B = 36;           // pyramid blocks per img
constexpr int S0_A = 62;            // s0 tiles in kernel A
constexpr int S0_B = 34;            // s0 tiles in kernel B (62..95)
constexpr int REST_B = 34;          // s1-4 tiles per img

// gauss(11, sigma=1.5), normalized (matches expf path to fp32 ulp).
__device__ constexpr float GW[11] = {
    0.00102838f, 0.00759875f, 0.03600077f, 0.10936070f, 0.21300553f,
    0.26601172f,
    0.21300553f, 0.10936070f, 0.03600077f, 0.00759875f, 0.00102838f};

typedef float f2 __attribute__((ext_vector_type(2)));
typedef float f4 __attribute__((ext_vector_type(4)));

// ---- VOP3P packed fp32 with op_sel variants ----
// op_sel[i]: half feeding LOW result (0=lo); op_sel_hi[i]: half feeding HIGH.
__device__ __forceinline__ f2 pk_mul(f2 a, f2 b) {
  f2 d;
  asm("v_pk_mul_f32 %0, %1, %2" : "=v"(d) : "v"(a), "v"(b));
  return d;
}
// d = a * splat_lo(b)  (init of hblur chain, j=0 even term)
__device__ __forceinline__ f2 pk_mul_s1lo(f2 a, f2 b) {
  f2 d;
  asm("v_pk_mul_f32 %0, %1, %2 op_sel:[0,0] op_sel_hi:[1,0]"
      : "=v"(d) : "v"(a), "v"(b));
  return d;
}
// d += splat_lo(q) * p   (vblur tap: weight splat from pair reg)
__device__ __forceinline__ void fma_w(f2& d, f2 q, f2 p) {
  asm("v_pk_fma_f32 %0, %1, %2, %0 op_sel:[0,0,0] op_sel_hi:[0,1,1]"
      : "+v"(d) : "v"(q), "v"(p));
}
// d += q * splat_lo(t)
__device__ __forceinline__ void fma_nl(f2& d, f2 q, f2 t) {
  asm("v_pk_fma_f32 %0, %1, %2, %0 op_sel:[0,0,0] op_sel_hi:[1,0,1]"
      : "+v"(d) : "v"(q), "v"(t));
}
// d += q * splat_hi(t)
__device__ __forceinline__ void fma_nh(f2& d, f2 q, f2 t) {
  asm("v_pk_fma_f32 %0, %1, %2, %0 op_sel:[0,1,0] op_sel_hi:[1,1,1]"
      : "+v"(d) : "v"(q), "v"(t));
}
// d += swap(q) * splat_lo(t)
__device__ __forceinline__ void fma_sl(f2& d, f2 q, f2 t) {
  asm("v_pk_fma_f32 %0, %1, %2, %0 op_sel:[1,0,0] op_sel_hi:[0,0,1]"
      : "+v"(d) : "v"(q), "v"(t));
}
// d += swap(q) * splat_hi(t)
__device__ __forceinline__ void fma_sh(f2& d, f2 q, f2 t) {
  asm("v_pk_fma_f32 %0, %1, %2, %0 op_sel:[1,1,0] op_sel_hi:[0,1,1]"
      : "+v"(d) : "v"(q), "v"(t));
}

// lane i <- lane i+1 (wave_shl:1); lane 63 gets 0. HW-verified (R5-R7).
__device__ __forceinline__ float wshl1(float v) {
  return __int_as_float(__builtin_amdgcn_mov_dpp(
      __float_as_int(v), 0x130, 0xF, 0xF, true));
}
__device__ __forceinline__ f2 wshl1v(f2 v) {
  f2 r;
  r.x = wshl1(v.x);
  r.y = wshl1(v.y);
  return r;
}

// Fully-hoisted vertical blur (R11/R14 known-good): all 14 rows staged in
// registers, THEN the tap loop; wave pays global latency once. BASE: two
// f2 loads/row (X0,Y0), u/w formed in-kernel. !BASE: one f4 load/row from
// the interleaved plane (Pu=v.xy, Pw=v.zw).
template <bool BASE, bool CLAMP>
__device__ __forceinline__ void vblur(const float* __restrict__ XP,
                                      const float* __restrict__ YP, int row0,
                                      int W2, int H, int cp, f2 (&AU)[4],
                                      f2 (&AW)[4], f2 (&BU)[4], f2 (&BW)[4],
                                      const f2 (&QQ)[6]) {
  const f2* PA = (const f2*)XP;
  const f2* PB = (const f2*)YP;
  const f4* PV = (const f4*)XP;
  f2 sa[14], sb[14];
  f4 sv[14];
#pragma unroll
  for (int j = 0; j < 14; ++j) {
    int rin = row0 + j;
    if (CLAMP) rin = rin < H - 1 ? rin : H - 1;
    const int off = rin * W2 + cp;      // 32-bit affine (fits: <= 384*192)
    if (BASE) {
      sa[j] = PA[off];
      sb[j] = PB[off];
    } else {
      sv[j] = PV[off];
    }
  }
  __builtin_amdgcn_sched_barrier(0);    // keep stage loads hoisted
#pragma unroll
  for (int j = 0; j < 14; ++j) {
    f2 Pu, Pw;
    if (BASE) {
      f2 pa = sa[j], pb = sb[j];
      Pu = pa + pb;
      Pw = pa - pb;
    } else {
      f4 v = sv[j];
      Pu.x = v.x; Pu.y = v.y;
      Pw.x = v.z; Pw.y = v.w;
    }
    f2 Qu = pk_mul(Pu, Pu), Qw = pk_mul(Pw, Pw);
#pragma unroll
    for (int i = 0; i < 4; ++i) {
      const int k = j - i;
      if (k >= 0 && k <= 10) {
        const int qi = k <= 5 ? k : 10 - k;     // G[k] = QQ[qi].x
        fma_w(AU[i], QQ[qi], Pu);
        fma_w(AW[i], QQ[qi], Pw);
        fma_w(BU[i], QQ[qi], Qu);
        fma_w(BW[i], QQ[qi], Qw);
      }
    }
  }
}

// One SSIM tile: 64 lanes x 2 cols = 128 input cols -> up to 118 outputs;
// 4 output rows/wave, 4 waves = 16 output rows (26 input rows) per block.
template <bool BASE>
__device__ __forceinline__ void ssim_tile(const float* __restrict__ XP,
                                          const float* __restrict__ YP,
                                          int H, int x0, int tw, int by,
                                          int s, int img,
                                          float* __restrict__ acc) {
  __shared__ float red[2][4];
  const int W2 = H >> 1, OH = H - 10;
  const int t = threadIdx.x;
  const int lane = t & 63, wv = t >> 6;
  int cp = (x0 >> 1) + lane;
  cp = cp < W2 - 1 ? cp : W2 - 1;
  const int row0 = by * 16 + wv * 4;

  // Weight pairs QQ[n] = (G[n], G[n-1]), G[-1]=0. All other weight forms
  // derived via op_sel (splat-lo / swap) using G[k] = G[10-k].
  f2 QQ[6];
  QQ[0].x = GW[0]; QQ[0].y = 0.f;
#pragma unroll
  for (int n = 1; n < 6; ++n) { QQ[n].x = GW[n]; QQ[n].y = GW[n - 1]; }

  float ssim_s = 0.f, cs_s = 0.f;

  if (row0 < OH) {
    f2 AU[4] = {}, AW[4] = {}, BU[4] = {}, BW[4] = {};
    const bool noclamp = (row0 + 13 <= H - 1);
    if (noclamp) vblur<BASE, false>(XP, YP, row0, W2, H, cp, AU, AW, BU, BW, QQ);
    else         vblur<BASE, true >(XP, YP, row0, W2, H, cp, AU, AW, BU, BW, QQ);

    // hblur: 2 outputs/lane, 5 two-col shift steps.
    // O.x = sum_k G[k]*V[2c+k], O.y = sum_k G[k]*V[2c+1+k]; contribution of
    // t_j=(e,o)=(V[2c+2j],V[2c+2j+1]): (G[2j],G[2j-1])*e + (G[2j+1],G[2j])*o.
    auto hb = [&QQ](f2 tt) -> f2 {
      f2 h = pk_mul_s1lo(QQ[0], tt);   // j=0: (G0,0)*e
      fma_nh(h, QQ[1], tt);            // j=0: (G1,G0)*o
      tt = wshl1v(tt);
      fma_nl(h, QQ[2], tt);            // j=1: (G2,G1)*e
      fma_nh(h, QQ[3], tt);            // j=1: (G3,G2)*o
      tt = wshl1v(tt);
      fma_nl(h, QQ[4], tt);            // j=2: (G4,G3)*e
      fma_nh(h, QQ[5], tt);            // j=2: (G5,G4)*o
      tt = wshl1v(tt);
      fma_sl(h, QQ[5], tt);            // j=3: (G6,G5)=(G4,G5)=swap(QQ5)
      fma_sh(h, QQ[4], tt);            // j=3: (G7,G6)=(G3,G4)=swap(QQ4)
      tt = wshl1v(tt);
      fma_sl(h, QQ[3], tt);            // j=4: (G8,G7)=swap(QQ3)
      fma_sh(h, QQ[2], tt);            // j=4: (G9,G8)=swap(QQ2)
      tt = wshl1v(tt);
      fma_sl(h, QQ[1], tt);            // j=5: (G10,G9)=swap(QQ1)
      fma_sh(h, QQ[0], tt);            // j=5: (0,G10)=swap(QQ0)
      return h;
    };

    const bool vx = (2 * lane) < tw;
    const bool vy = (2 * lane + 1) < tw;
#pragma unroll
    for (int i = 0; i < 4; ++i) {
      if (row0 + i < OH) {
        f2 bU = hb(AU[i]), bW = hb(AW[i]);
        f2 bU2 = hb(BU[i]), bW2 = hb(BW[i]);
        f2 m2u = pk_mul(bU, bU), m2w = pk_mul(bW, bW);
        f2 Pm = m2u - m2w;           // 4*mu1*mu2
        f2 Qm = m2u + m2w;           // 2*(mu1^2+mu2^2)
        f2 Am = bU2 - bW2;           // 4*E[xy]
        f2 Bm = bU2 + bW2;           // 2*(E[xx]+E[yy])
        float csx = (Am.x - Pm.x + TWO_C2) *
                    __builtin_amdgcn_rcpf(Bm.x - Qm.x + TWO_C2);
        float lx = (Pm.x + TWO_C1) * __builtin_amdgcn_rcpf(Qm.x + TWO_C1);
        float csy = (Am.y - Pm.y + TWO_C2) *
                    __builtin_amdgcn_rcpf(Bm.y - Qm.y + TWO_C2);
        float ly = (Pm.y + TWO_C1) * __builtin_amdgcn_rcpf(Qm.y + TWO_C1);
        if (vx) { cs_s += csx; ssim_s += lx * csx; }
        if (vy) { cs_s += csy; ssim_s += ly * csy; }
      }
    }
  }

  // ---- reduce: wave shuffle -> LDS -> 2 atomics/block ----
#pragma unroll
  for (int off = 32; off > 0; off >>= 1) {
    ssim_s += __shfl_down(ssim_s, off);
    cs_s += __shfl_down(cs_s, off);
  }
  if (lane == 0) { red[0][wv] = ssim_s; red[1][wv] = cs_s; }
  __syncthreads();
  if (t == 0) {
    atomicAdd(&acc[(2 * s + 0) * NIMG + img],
              red[0][0] + red[0][1] + red[0][2] + red[0][3]);
    atomicAdd(&acc[(2 * s + 1) * NIMG + img],
              red[1][0] + red[1][1] + red[1][2] + red[1][3]);
  }
}

// Coalesced pyramid body: one wave owns a 64x16 source tile (two 8-row
// batches); dwordx4 loads, float4 stores, u/w interleaved per col-pair.
__device__ __forceinline__ void pyramid_body(
    const float* __restrict__ X, const float* __restrict__ Y,
    float* __restrict__ i1, float* __restrict__ i2,
    float* __restrict__ i3, float* __restrict__ i4, int img, int bx) {
  const int t = threadIdx.x;
  const int wv = t >> 6, lane = t & 63;
  const int tidx = bx * 4 + wv;             // 0..143
  const int tx = tidx % 6, ty = tidx / 6;   // 6 x 24 tiles of 64x16
  const int r = lane >> 4, c = lane & 15;

  const float* Xs = X + (size_t)img * 384 * 384;
  const float* Ys = Y + (size_t)img * 384 * 384;
  f4* p1 = (f4*)i1 + (size_t)img * 192 * 96;
  f4* p2 = (f4*)i2 + (size_t)img * 96 * 48;
  f4* p3 = (f4*)i3 + (size_t)img * 48 * 24;
  f4* p4 = (f4*)i4 + (size_t)img * 24 * 12;

  float h4u = 0.f, h4w = 0.f;
#pragma unroll
  for (int b = 0; b < 2; ++b) {
    const int gr = ty * 16 + b * 8 + 2 * r;
    const int gc = tx * 64 + 4 * c;
    f4 xu = *(const f4*)&Xs[(size_t)gr * 384 + gc];
    f4 xv = *(const f4*)&Xs[(size_t)(gr + 1) * 384 + gc];
    f4 yu = *(const f4*)&Ys[(size_t)gr * 384 + gc];
    f4 yv = *(const f4*)&Ys[(size_t)(gr + 1) * 384 + gc];
    float ax = 0.25f * (xu.x + xu.y + xv.x + xv.y);   // L1 of X @ C1
    float bx2 = 0.25f * (xu.z + xu.w + xv.z + xv.w);  // L1 of X @ C1+1
    float ay = 0.25f * (yu.x + yu.y + yv.x + yv.y);
    float by2 = 0.25f * (yu.z + yu.w + yv.z + yv.w);
    float u0 = ax + ay, u1v = bx2 + by2, w0 = ax - ay, w1v = bx2 - by2;
    {  // L1: row ty*8+4b+r, colpair tx*16+c  (16 lanes x 16B = 256B)
      f4 st; st.x = u0; st.y = u1v; st.z = w0; st.w = w1v;
      p1[(size_t)(ty * 8 + b * 4 + r) * 96 + tx * 16 + c] = st;
    }
    // L2: horizontal in-lane, vertical via r-pair (lane^16).
    float hu = u0 + u1v, hw = w0 + w1v;
    float su = 0.25f * (hu + __shfl_xor(hu, 16));     // L2 @ (R2, tx*16+c)
    float sw = 0.25f * (hw + __shfl_xor(hw, 16));
    float suh = __shfl_xor(su, 1), swh = __shfl_xor(sw, 1);
    if ((r & 1) == 0 && (c & 1) == 0) {
      f4 st; st.x = su; st.y = suh; st.z = sw; st.w = swh;
      p2[(size_t)(ty * 4 + 2 * b + (r >> 1)) * 48 + tx * 8 + (c >> 1)] = st;
    }
    // L3: col pair via lane^1, row pair via lane^32 (r 0<->2).
    float au = su + __shfl_xor(su, 1);
    float aw = sw + __shfl_xor(sw, 1);
    float u3 = 0.25f * (au + __shfl_xor(au, 32));     // L3 @ (ty*2+b, tx*8+(c>>1))
    float w3 = 0.25f * (aw + __shfl_xor(aw, 32));
    float u3h = __shfl_xor(u3, 2), w3h = __shfl_xor(w3, 2);
    if (r == 0 && (c & 3) == 0) {
      f4 st; st.x = u3; st.y = u3h; st.z = w3; st.w = w3h;
      p3[(size_t)(ty * 2 + b) * 24 + tx * 4 + (c >> 2)] = st;
    }
    // L4: col pair via lane^2, row pair across batches (kept in regs).
    float hu4 = u3 + __shfl_xor(u3, 2);
    float hw4 = w3 + __shfl_xor(w3, 2);
    if (b == 0) {
      h4u = hu4; h4w = hw4;
    } else {
      float l4u = 0.25f * (h4u + hu4), l4w = 0.25f * (h4w + hw4);
      float l4uh = __shfl_xor(l4u, 4), l4wh = __shfl_xor(l4w, 4);
      if (r == 0 && (c & 7) == 0) {
        f4 st; st.x = l4u; st.y = l4uh; st.z = l4w; st.w = l4wh;
        p4[(size_t)ty * 12 + tx * 2 + (c >> 3)] = st;
      }
    }
  }
}

// Run one s0 tile by linear tile index 0..95 (4 x 24 grid).
__device__ __forceinline__ void s0_tile(const float* __restrict__ X,
                                        const float* __restrict__ Y, int img,
                                        int lt, float* __restrict__ acc) {
  const int tx = lt & 3, by = lt >> 2;
  const int x0 = tx * 94;
  int tw = 374 - x0;
  tw = tw < 94 ? tw : 94;
  ssim_tile<true>(X + (size_t)img * 384 * 384, Y + (size_t)img * 384 * 384,
                  384, x0, tw, by, 0, img, acc);
}

// Kernel A: blocks [0..35] pyramid, [36..97] s0 tiles 0..61.
__global__ __launch_bounds__(256, 4) void fused_pyr_s0(
    const float* __restrict__ X, const float* __restrict__ Y,
    float* __restrict__ i1, float* __restrict__ i2,
    float* __restrict__ i3, float* __restrict__ i4,
    float* __restrict__ acc) {
  const int img = blockIdx.y;
  if (blockIdx.x < PYR_B) {
    pyramid_body(X, Y, i1, i2, i3, i4, img, blockIdx.x);
    return;
  }
  s0_tile(X, Y, img, blockIdx.x - PYR_B, acc);
}

// Kernel B: blocks [0..33] s1-4 tiles (need pyramid; stream-ordered after
// A), [34..67] s0 tiles 62..95 (latency cover for the rest tiles).
// Rest tiles dispatch FIRST so their stalls overlap s0 blocks behind them.
__global__ __launch_bounds__(256, 4) void ssim_mix(
    const float* __restrict__ X, const float* __restrict__ Y,
    const float* __restrict__ i1, const float* __restrict__ i2,
    const float* __restrict__ i3, const float* __restrict__ i4,
    float* __restrict__ acc) {
  const int img = blockIdx.y;
  if (blockIdx.x >= REST_B) {
    s0_tile(X, Y, img, 62 + (blockIdx.x - REST_B), acc);
    return;
  }
  const int tile = 96 + blockIdx.x;      // 96..129
  int s;
  if (tile < 120) s = 1;
  else if (tile < 126) s = 2;
  else if (tile < 129) s = 3;
  else s = 4;
  const int tstart[5] = {0, 96, 120, 126, 129};
  const int HH[5] = {384, 192, 96, 48, 24};
  const int NTX[5] = {4, 2, 1, 1, 1};
  const int TWM[5] = {94, 92, 86, 38, 14};
  const int lt = tile - tstart[s];
  const int H = HH[s], OW = H - 10;
  const int tx = lt % NTX[s], by = lt / NTX[s];
  const int x0 = tx * TWM[s];
  const int tw = (TWM[s] < OW - x0) ? TWM[s] : OW - x0;
  const float* ip = (s == 1) ? i1 : (s == 2) ? i2 : (s == 3) ? i3 : i4;
  const float* XP = ip + (size_t)img * H * (H >> 1) * 4;
  ssim_tile<false>(XP, nullptr, H, x0, tw, by, s, img, acc);
}

// acc layout: acc[s*2+0][img] = ssim sum, acc[s*2+1][img] = cs sum.
__global__ void final_kernel(const float* __restrict__ acc,
                             float* __restrict__ out) {
  __shared__ float prods[NIMG];
  const float wts[5] = {0.0448f, 0.2856f, 0.3001f, 0.2363f, 0.1333f};
  const float inv_npix[5] = {1.f / (374.f * 374.f), 1.f / (182.f * 182.f),
                             1.f / (86.f * 86.f),  1.f / (38.f * 38.f),
                             1.f / (14.f * 14.f)};
  int t = threadIdx.x;
  if (t < NIMG) {
    float p = 1.f;
#pragma unroll
    for (int s = 0; s < 5; ++s) {
      float sum = (s < 4) ? acc[(s * 2 + 1) * NIMG + t]
                          : acc[(s * 2 + 0) * NIMG + t];
      float m = sum * inv_npix[s];
      m = m > 0.f ? m : 0.f;
      p *= powf(m, wts[s]);
    }
    prods[t] = p;
  }
  __syncthreads();
  if (t == 0) {
    float s = 0.f;
    for (int i = 0; i < NIMG; ++i) s += prods[i];
    out[0] = 1.f - s / (float)NIMG;
  }
}

}  // namespace

extern "C" void kernel_launch(void* const* d_in, const int* in_sizes, int n_in,
                              void* d_out, int out_size, void* d_ws,
                              size_t ws_size, hipStream_t stream) {
  const float* X0 = (const float*)d_in[0];
  const float* Y0 = (const float*)d_in[1];
  float* out = (float*)d_out;
  float* ws = (float*)d_ws;

  // Interleaved u/w planes: level L holds 2*H*W floats.
  const size_t L1 = (size_t)NIMG * 192 * 192 * 2;
  const size_t L2 = (size_t)NIMG * 96 * 96 * 2;
  const size_t L3 = (size_t)NIMG * 48 * 48 * 2;
  const size_t L4 = (size_t)NIMG * 24 * 24 * 2;

  float* i1 = ws;
  float* i2 = i1 + L1;
  float* i3 = i2 + L2;
  float* i4 = i3 + L3;
  float* acc = i4 + L4;  // 10*NIMG floats

  hipMemsetAsync(acc, 0, 10 * NIMG * sizeof(float), stream);

  fused_pyr_s0<<<dim3(PYR_B + S0_A, NIMG), dim3(256), 0, stream>>>(
      X0, Y0, i1, i2, i3, i4, acc);

  ssim_mix<<<dim3(REST_B + S0_B, NIMG), dim3(256), 0, stream>>>(
      X0, Y0, i1, i2, i3, i4, acc);

  final_kernel<<<dim3(1), dim3(128), 0, stream>>>(acc, out);
}